// Round 2
// baseline (170.748 us; speedup 1.0000x reference)
//
#include <hip/hip_runtime.h>
#include <float.h>

#define B_SZ   64
#define T_FR   20
#define K_SEL  5
#define C_CH   3
#define D_SKIM 245760
#define HW224  50176
#define F4_IMG 12544        // HW224/4
#define K1_BLOCKS 768
#define K1_TILES  5         // 768 * 5 * 64 == 245760
#define GP_PARTS  4
#define F4_PART   3136      // F4_IMG/4

// ---------------------------------------------------------------------------
// Kernel 1: per-block partial of fea = A[64,245760] @ W[245760,64].
// 768 blocks (3/CU), each covers 5 tiles of BK=64. 4 waves split each tile's
// d-range (16 d each); every wave holds a full 64x64 partial in an 8x8
// register tile (64 FMA per 2 LDS b128 reads -> LDS no longer the bottleneck).
// A-tile LDS: stride 64 + XOR swizzle (col ^ ((row&7)<<2)) -> the 8 broadcast
// addresses of each A-fragment read cover all 8 bank-quads (conflict-free).
// W-tile: stride 68 (2-way banks = free). Epilogue: deterministic 4-round
// cross-wave reduce in LDS, then coalesced partial-slab write.
// ---------------------------------------------------------------------------
__global__ __launch_bounds__(256, 3) void skim_gemm(
    const float* __restrict__ A, const float* __restrict__ W,
    float* __restrict__ partial) {
  __shared__ float lds[8448];          // As[64*64] swizzled | Ws[64][68]
  float* As = lds;
  float* Ws = lds + 4096;
  const int t    = threadIdx.x;
  const int lane = t & 63;
  const int wav  = t >> 6;             // 0..3
  const int bo   = lane >> 3;          // 0..7
  const int jo   = lane & 7;           // 0..7
  const int b0   = bo << 3;
  const int j0   = jo << 3;
  const int srow = t >> 4;             // 0..15 (staging)
  const int scol = (t & 15) << 2;      // 0..60 (staging)

  float acc[8][8];
#pragma unroll
  for (int i = 0; i < 8; ++i)
#pragma unroll
    for (int j = 0; j < 8; ++j) acc[i][j] = 0.f;

  for (int tile = 0; tile < K1_TILES; ++tile) {
    const long d0 = (long)(blockIdx.x * K1_TILES + tile) * 64;
    __syncthreads();                   // LDS safe from previous tile readers
#pragma unroll
    for (int p = 0; p < 4; ++p) {
      const int row = (p << 4) + srow; // 0..63
      float4 a4 = *reinterpret_cast<const float4*>(A + (long)row * D_SKIM + d0 + scol);
      *reinterpret_cast<float4*>(&As[(row << 6) + (scol ^ ((row & 7) << 2))]) = a4;
      float4 w4 = *reinterpret_cast<const float4*>(W + (d0 + row) * 64 + scol);
      *reinterpret_cast<float4*>(&Ws[row * 68 + scol]) = w4;
    }
    __syncthreads();
#pragma unroll
    for (int dg = 0; dg < 4; ++dg) {
      const int d4 = (wav << 4) + (dg << 2);
      float4 a[8];
#pragma unroll
      for (int i = 0; i < 8; ++i)
        a[i] = *reinterpret_cast<const float4*>(&As[((b0 + i) << 6) + (d4 ^ (i << 2))]);
#pragma unroll
      for (int dp = 0; dp < 4; ++dp) {
        const float4 wlo = *reinterpret_cast<const float4*>(&Ws[(d4 + dp) * 68 + j0]);
        const float4 whi = *reinterpret_cast<const float4*>(&Ws[(d4 + dp) * 68 + j0 + 4]);
#pragma unroll
        for (int i = 0; i < 8; ++i) {
          const float av = reinterpret_cast<const float*>(&a[i])[dp];
          acc[i][0] = fmaf(av, wlo.x, acc[i][0]);
          acc[i][1] = fmaf(av, wlo.y, acc[i][1]);
          acc[i][2] = fmaf(av, wlo.z, acc[i][2]);
          acc[i][3] = fmaf(av, wlo.w, acc[i][3]);
          acc[i][4] = fmaf(av, whi.x, acc[i][4]);
          acc[i][5] = fmaf(av, whi.y, acc[i][5]);
          acc[i][6] = fmaf(av, whi.z, acc[i][6]);
          acc[i][7] = fmaf(av, whi.w, acc[i][7]);
        }
      }
    }
  }
  // deterministic cross-wave reduce into lds[0..4095] (aliases As)
  __syncthreads();
  for (int r = 0; r < 4; ++r) {
    if (wav == r) {
#pragma unroll
      for (int i = 0; i < 8; ++i)
#pragma unroll
        for (int jj = 0; jj < 8; ++jj) {
          const int c = (jj + bo) & 7;           // bank-skew: 2-way max
          const int addr = ((b0 + i) << 6) + j0 + c;
          if (r == 0) lds[addr] = acc[i][c];
          else        lds[addr] += acc[i][c];
        }
    }
    __syncthreads();
  }
  float* out = partial + (long)blockIdx.x * 4096;
#pragma unroll
  for (int k = 0; k < 16; ++k) out[(k << 8) + t] = lds[(k << 8) + t];
}

// ---------------------------------------------------------------------------
// Kernel 2: reduce 768 partial slabs -> fea[b][j]; relu(+b_skim); logits via
// W_pol; stable top-5 (lowest index on ties, = jax.lax.top_k), sorted asc.
// One block (4 waves) per batch row; waves split the 768-way reduction.
// ---------------------------------------------------------------------------
__global__ __launch_bounds__(256) void policy_topk(
    const float* __restrict__ partial, const float* __restrict__ b_skim,
    const float* __restrict__ W_pol, const float* __restrict__ b_pol,
    int* __restrict__ idx_out) {
  const int b    = blockIdx.x;
  const int t    = threadIdx.x;
  const int lane = t & 63;
  const int wav  = t >> 6;
  __shared__ float red[4][64];
  __shared__ float vsh[64];
  __shared__ float lgsh[20];

  const int P4 = K1_BLOCKS / 4;        // 192 slabs per wave
  const float* base = partial + (long)(wav * P4) * 4096 + b * 64 + lane;
  float s = 0.f;
#pragma unroll 16
  for (int p = 0; p < P4; ++p) s += base[(long)p * 4096];
  red[wav][lane] = s;
  __syncthreads();

  if (wav == 0) {
    float fea = ((red[0][lane] + red[1][lane]) + (red[2][lane] + red[3][lane]))
                + b_skim[lane];
    vsh[lane] = fmaxf(fea, 0.f);
  }
  __syncthreads();

  if (t < 20) {
    float lg = b_pol[t];
#pragma unroll 8
    for (int k = 0; k < 64; ++k) lg = fmaf(vsh[k], W_pol[k * 20 + t], lg);
    lgsh[t] = lg;
  }
  __syncthreads();

  if (t == 0) {
    float lg[20];
#pragma unroll
    for (int i = 0; i < 20; ++i) lg[i] = lgsh[i];
    int sel[K_SEL];
#pragma unroll
    for (int s5 = 0; s5 < K_SEL; ++s5) {
      int bi = 0; float bv = lg[0];
      for (int i = 1; i < 20; ++i)
        if (lg[i] > bv) { bv = lg[i]; bi = i; }   // strict >: lowest idx wins
      sel[s5] = bi; lg[bi] = -FLT_MAX;
    }
#pragma unroll
    for (int a = 1; a < K_SEL; ++a) {
      int v = sel[a], c = a;
      while (c > 0 && sel[c - 1] > v) { sel[c] = sel[c - 1]; --c; }
      sel[c] = v;
    }
#pragma unroll
    for (int s5 = 0; s5 < K_SEL; ++s5) idx_out[b * K_SEL + s5] = sel[s5];
  }
}

// ---------------------------------------------------------------------------
// Kernel 3: partial spatial sums of the 5 selected frames.
// 4 parts per (b,s,c) image -> 3840 blocks == exactly 15 blocks/CU (no tail).
// ---------------------------------------------------------------------------
__global__ __launch_bounds__(256) void gather_pool(
    const float* __restrict__ F224, const int* __restrict__ idx,
    float* __restrict__ pooled_part) {
  const int blk  = blockIdx.x;
  const int part = blk & 3;
  const int img  = blk >> 2;           // b*15 + s*3 + c
  const int b = img / 15;
  const int r = img % 15;
  const int s = r / 3;
  const int c = r % 3;
  const int fr = idx[b * K_SEL + s];
  const float4* p4 = reinterpret_cast<const float4*>(F224) +
      ((long)(b * T_FR + fr) * C_CH + c) * F4_IMG + part * F4_PART;
  float sum = 0.f;
#pragma unroll 4
  for (int i = threadIdx.x; i < F4_PART; i += 256) {
    float4 v = p4[i];
    sum += (v.x + v.y) + (v.z + v.w);
  }
#pragma unroll
  for (int off = 32; off; off >>= 1) sum += __shfl_down(sum, off);
  __shared__ float red[4];
  if ((threadIdx.x & 63) == 0) red[threadIdx.x >> 6] = sum;
  __syncthreads();
  if (threadIdx.x == 0) pooled_part[blk] = (red[0] + red[1]) + (red[2] + red[3]);
}

// ---------------------------------------------------------------------------
// Kernel 4: out[b][n] = b_eval[n] + sum_k pooled[b][k] * W_eval[k][n]
// One block per b; fold the 4-part sum + 1/HW224 scaling here.
// ---------------------------------------------------------------------------
__global__ __launch_bounds__(512) void eval_gemm(
    const float* __restrict__ pooled_part, const float* __restrict__ W_eval,
    const float* __restrict__ b_eval, float* __restrict__ out) {
  const int b = blockIdx.x;
  const int t = threadIdx.x;
  __shared__ float sh[60];
  __shared__ float pk[15];
  if (t < 60) sh[t] = pooled_part[b * 60 + t];
  __syncthreads();
  if (t < 15)
    pk[t] = ((sh[t * 4] + sh[t * 4 + 1]) + (sh[t * 4 + 2] + sh[t * 4 + 3]))
            * (1.0f / HW224);
  __syncthreads();
  if (t < 400) {
    float o = b_eval[t];
#pragma unroll
    for (int k = 0; k < 15; ++k) o = fmaf(pk[k], W_eval[k * 400 + t], o);
    out[b * 400 + t] = o;
  }
}

// ---------------------------------------------------------------------------
extern "C" void kernel_launch(void* const* d_in, const int* in_sizes, int n_in,
                              void* d_out, int out_size, void* d_ws, size_t ws_size,
                              hipStream_t stream) {
  const float* F64    = (const float*)d_in[0];
  const float* F224   = (const float*)d_in[1];
  const float* W_skim = (const float*)d_in[2];
  const float* b_skim = (const float*)d_in[3];
  const float* W_pol  = (const float*)d_in[4];
  const float* b_pol  = (const float*)d_in[5];
  const float* W_eval = (const float*)d_in[6];
  const float* b_eval = (const float*)d_in[7];
  float* out = (float*)d_out;

  char* ws = (char*)d_ws;
  float* partial     = (float*)ws;                         // 768*4096 floats = 12.58 MB
  int*   idx         = (int*)(ws + (size_t)K1_BLOCKS * 4096 * 4);
  float* pooled_part = (float*)(ws + (size_t)K1_BLOCKS * 4096 * 4 + 1280);

  skim_gemm  <<<K1_BLOCKS, 256, 0, stream>>>(F64, W_skim, partial);
  policy_topk<<<B_SZ, 256, 0, stream>>>(partial, b_skim, W_pol, b_pol, idx);
  gather_pool<<<B_SZ * K_SEL * C_CH * GP_PARTS, 256, 0, stream>>>(F224, idx, pooled_part);
  eval_gemm  <<<B_SZ, 512, 0, stream>>>(pooled_part, W_eval, b_eval, out);
}